// Round 1
// baseline (743.243 us; speedup 1.0000x reference)
//
#include <hip/hip_runtime.h>
#include <math.h>

typedef __bf16 bf16;
typedef bf16 bf16x8 __attribute__((ext_vector_type(8)));
typedef bf16 bf16x4 __attribute__((ext_vector_type(4)));
typedef float f32x4 __attribute__((ext_vector_type(4)));

// ---------------- workspace layout (byte offsets) ----------------
// globals: 4*32*1024 f32          = 524288
// h_ws   : 8*32*256 f32           = 262144
// score  : 8*32 f32               = 1024
// cond   : 8 f32 (+pad)           = 1024
// part   : 4*8*32*1024 f32        = 4194304
// proj   : 2*128*32*1024 f32      = 33554432
// wT f2s : 2*5120*1024 bf16       = 20971520
// wT s2f : 1024*1024 bf16         = 2097152
#define OFF_GLOB   0ul
#define OFF_H      524288ul
#define OFF_SCORE  786432ul
#define OFF_COND   787456ul
#define OFF_PART   788480ul
#define OFF_PROJ   5242880ul
#define OFF_WTF2S  38797312ul
#define OFF_WTS2F  59768832ul
// total = 61865984 bytes (~59 MB)

// out layout: out0 @0 (512*32*1024), out1 @16777216, out2 @33554432 (128*32*1024), out3 @37748736

// ---------------- pair slots ----------------
// slot 0..3: slow->fast  (2,0)(3,0)(2,1)(3,1) ; slot 4..7: fast->slow (0,2)(1,2)(0,3)(1,3)
__device__ __forceinline__ void slot_ij(int s, int& i, int& j) {
  if (s < 4) { i = 2 + (s & 1); j = s >> 1; }
  else       { int ss = s - 4; i = ss & 1; j = 2 + (ss >> 1); }
}

// ---------------- means ----------------
__global__ __launch_bounds__(256) void k_means_part(
    const float* __restrict__ f0, const float* __restrict__ f1,
    const float* __restrict__ f2, const float* __restrict__ f3,
    float* __restrict__ part)
{
  int b = blockIdx.x, c = blockIdx.y, i = blockIdx.z, tid = threadIdx.x;
  const float* f = (i == 0) ? f0 : (i == 1) ? f1 : (i == 2) ? f2 : f3;
  int chunk = (i < 2) ? 64 : 16;
  int t0 = c * chunk;
  float4 s = make_float4(0.f, 0.f, 0.f, 0.f);
  for (int t = t0; t < t0 + chunk; ++t) {
    float4 v = ((const float4*)(f + (size_t)(t * 32 + b) * 1024))[tid];
    s.x += v.x; s.y += v.y; s.z += v.z; s.w += v.w;
  }
  ((float4*)part)[(size_t)((i * 8 + c) * 32 + b) * 256 + tid] = s;
}

__global__ __launch_bounds__(256) void k_means_final(
    const float* __restrict__ part, float* __restrict__ g)
{
  int b = blockIdx.x, i = blockIdx.y, tid = threadIdx.x;
  float4 s = make_float4(0.f, 0.f, 0.f, 0.f);
  for (int c = 0; c < 8; ++c) {
    float4 v = ((const float4*)part)[(size_t)((i * 8 + c) * 32 + b) * 256 + tid];
    s.x += v.x; s.y += v.y; s.z += v.z; s.w += v.w;
  }
  float inv = (i < 2) ? (1.f / 512.f) : (1.f / 128.f);
  s.x *= inv; s.y *= inv; s.z *= inv; s.w *= inv;
  ((float4*)g)[(size_t)(i * 32 + b) * 256 + tid] = s;
}

// ---------------- MLP layer 1 (partial, k-split, atomic accumulate) ----------------
__global__ __launch_bounds__(256) void k_mlp1(
    const float* __restrict__ g, const float* __restrict__ w1, float* __restrict__ h_ws)
{
  int s = blockIdx.x, hc = blockIdx.y, kz = blockIdx.z, tid = threadIdx.x;
  int pi, pj; slot_ij(s, pi, pj);
  int p = pi * 4 + pj;
  int h = hc * 32 + (tid & 31);
  int bg = tid >> 5;  // 0..7, handles b = bg*4 .. bg*4+3
  __shared__ float pv[32 * 65];
  float acc0 = 0.f, acc1 = 0.f, acc2 = 0.f, acc3 = 0.f;
  for (int kt = 0; kt < 8; ++kt) {
    int k0 = kz * 512 + kt * 64;
    __syncthreads();
    for (int l = tid; l < 2048; l += 256) {
      int bb = l >> 6, kk = l & 63;
      int k = k0 + kk;
      float v = (k < 1024) ? g[(size_t)pi * 32768 + bb * 1024 + k]
                           : g[(size_t)pj * 32768 + bb * 1024 + (k - 1024)];
      pv[bb * 65 + kk] = v;
    }
    __syncthreads();
    const float* wp = w1 + ((size_t)p * 2048 + k0) * 256 + hc * 32 + (tid & 31);
    for (int kk = 0; kk < 64; ++kk) {
      float w = wp[(size_t)kk * 256];
      acc0 += pv[(bg * 4 + 0) * 65 + kk] * w;
      acc1 += pv[(bg * 4 + 1) * 65 + kk] * w;
      acc2 += pv[(bg * 4 + 2) * 65 + kk] * w;
      acc3 += pv[(bg * 4 + 3) * 65 + kk] * w;
    }
  }
  atomicAdd(&h_ws[(size_t)s * 8192 + (bg * 4 + 0) * 256 + h], acc0);
  atomicAdd(&h_ws[(size_t)s * 8192 + (bg * 4 + 1) * 256 + h], acc1);
  atomicAdd(&h_ws[(size_t)s * 8192 + (bg * 4 + 2) * 256 + h], acc2);
  atomicAdd(&h_ws[(size_t)s * 8192 + (bg * 4 + 3) * 256 + h], acc3);
}

// ---------------- MLP layer 2 + sigmoid + mean + cond ----------------
__global__ __launch_bounds__(256) void k_mlp2(
    const float* __restrict__ h_ws, const float* __restrict__ b1,
    const float* __restrict__ w2, const float* __restrict__ b2,
    float* __restrict__ score, float* __restrict__ cond)
{
  int s = blockIdx.x, tid = threadIdx.x;
  int pi, pj; slot_ij(s, pi, pj);
  int p = pi * 4 + pj;
  float w2v = w2[p * 256 + tid];
  float b1v = b1[p * 256 + tid];
  float b2v = b2[p];
  __shared__ float red[4];
  float tot = 0.f;
  for (int b = 0; b < 32; ++b) {
    float v = fmaxf(h_ws[(size_t)s * 8192 + b * 256 + tid] + b1v, 0.f) * w2v;
    for (int off = 32; off > 0; off >>= 1) v += __shfl_down(v, off);
    if ((tid & 63) == 0) red[tid >> 6] = v;
    __syncthreads();
    if (tid == 0) {
      float sum = red[0] + red[1] + red[2] + red[3] + b2v;
      float sc = 1.f / (1.f + expf(-sum));
      score[s * 32 + b] = sc;
      tot += sc;
    }
    __syncthreads();
  }
  if (tid == 0) cond[s] = (tot * (1.f / 32.f) >= 0.3f) ? 1.f : 0.f;
}

// ---------------- f2s weight transpose -> B^T [co][kappa=kk*1024+ci] bf16 ----------------
__global__ __launch_bounds__(256) void k_f2s_transpose(
    const float* __restrict__ w, const float* __restrict__ cond, bf16* __restrict__ wT)
{
  int z = blockIdx.y, co = blockIdx.x, tid = threadIdx.x;  // z: output j-2
  int sel = (cond[5 + 2 * z] > 0.5f) ? 1 : ((cond[4 + 2 * z] > 0.5f) ? 0 : -1);
  if (sel < 0) return;
  int widx = sel * 2 + z;  // F2S_IDX mapping
  __shared__ float buf[5120];
  const float* src = w + ((size_t)widx * 1024 + co) * 5120;  // [co][ci][kk] row
  for (int l = tid; l < 5120; l += 256) buf[l] = src[l];
  __syncthreads();
  bf16* dst = wT + (size_t)z * 5242880 + (size_t)co * 5120;
  for (int o = tid; o < 5120; o += 256) {
    int kk = o >> 10, ci = o & 1023;
    dst[o] = (bf16)buf[ci * 5 + kk];
  }
}

// ---------------- s2f weight convert (already [co][ci]) ----------------
__global__ __launch_bounds__(256) void k_s2f_convert(
    const float* __restrict__ w, bf16* __restrict__ wT)
{
  size_t gi = (size_t)blockIdx.x * 256 + threadIdx.x;  // float4 index, 262144 total
  float4 v = ((const float4*)w)[gi];
  bf16x4 o;
  o[0] = (bf16)v.x; o[1] = (bf16)v.y; o[2] = (bf16)v.z; o[3] = (bf16)v.w;
  *(bf16x4*)&wT[gi * 4] = o;
}

// ---------------- s2f projection GEMM: proj[z][t'*32+b][co] = conv1x1(feat_sel) + bias ----------------
__global__ __launch_bounds__(256) void k_s2f_gemm(
    const float* __restrict__ feat2, const float* __restrict__ feat3,
    const bf16* __restrict__ wT, const float* __restrict__ s2f_b,
    const float* __restrict__ cond, float* __restrict__ proj)
{
  int z = blockIdx.z;  // output j = z
  int sel = (cond[1 + 2 * z] > 0.5f) ? 3 : ((cond[2 * z] > 0.5f) ? 2 : -1);
  if (sel < 0) return;
  const float* A = (sel == 3) ? feat3 : feat2;
  float* projz = proj + (size_t)z * 4194304;
  int tid = threadIdx.x;
  int M0 = blockIdx.x * 128, N0 = blockIdx.y * 128;
  __shared__ bf16 As[128][72];
  __shared__ bf16 Bs[128][72];
  f32x4 acc[4][4];
  for (int a = 0; a < 4; ++a)
    for (int c = 0; c < 4; ++c) { acc[a][c][0] = 0.f; acc[a][c][1] = 0.f; acc[a][c][2] = 0.f; acc[a][c][3] = 0.f; }
  int row = tid >> 1, half = tid & 1;
  int lane = tid & 63, wv = tid >> 6;
  int wr = (wv >> 1) * 64, wc = (wv & 1) * 64;
  int rl = lane & 15, q = lane >> 4;
  for (int kt = 0; kt < 16; ++kt) {
    int ci0 = kt * 64;
    __syncthreads();
    {
      const float4* src = (const float4*)(A + (size_t)(M0 + row) * 1024 + ci0 + half * 32);
      #pragma unroll
      for (int u = 0; u < 4; ++u) {
        float4 v0 = src[2 * u], v1 = src[2 * u + 1];
        bf16x8 pk;
        pk[0] = (bf16)v0.x; pk[1] = (bf16)v0.y; pk[2] = (bf16)v0.z; pk[3] = (bf16)v0.w;
        pk[4] = (bf16)v1.x; pk[5] = (bf16)v1.y; pk[6] = (bf16)v1.z; pk[7] = (bf16)v1.w;
        *(bf16x8*)&As[row][half * 32 + u * 8] = pk;
      }
      const uint4* bs = (const uint4*)(wT + (size_t)(N0 + row) * 1024 + ci0 + half * 32);
      #pragma unroll
      for (int u = 0; u < 4; ++u) *(uint4*)&Bs[row][half * 32 + u * 8] = bs[u];
    }
    __syncthreads();
    #pragma unroll
    for (int ks = 0; ks < 2; ++ks) {
      bf16x8 af[4], bfv[4];
      #pragma unroll
      for (int mi = 0; mi < 4; ++mi) af[mi] = *(const bf16x8*)&As[wr + mi * 16 + rl][ks * 32 + q * 8];
      #pragma unroll
      for (int ni = 0; ni < 4; ++ni) bfv[ni] = *(const bf16x8*)&Bs[wc + ni * 16 + rl][ks * 32 + q * 8];
      #pragma unroll
      for (int mi = 0; mi < 4; ++mi)
        #pragma unroll
        for (int ni = 0; ni < 4; ++ni)
          acc[mi][ni] = __builtin_amdgcn_mfma_f32_16x16x32_bf16(af[mi], bfv[ni], acc[mi][ni], 0, 0, 0);
    }
  }
  #pragma unroll
  for (int mi = 0; mi < 4; ++mi)
    #pragma unroll
    for (int ni = 0; ni < 4; ++ni)
      #pragma unroll
      for (int r = 0; r < 4; ++r) {
        int gm = M0 + wr + mi * 16 + q * 4 + r;
        int gn = N0 + wc + ni * 16 + rl;
        projz[(size_t)gm * 1024 + gn] = acc[mi][ni][r] + s2f_b[gn];
      }
}

// ---------------- f2s strided-conv GEMM + residual epilogue -> out2/out3 ----------------
__global__ __launch_bounds__(256) void k_f2s_gemm(
    const float* __restrict__ feat0, const float* __restrict__ feat1,
    const float* __restrict__ feat2, const float* __restrict__ feat3,
    const bf16* __restrict__ wT, const float* __restrict__ score,
    const float* __restrict__ cond, float* __restrict__ out)
{
  int z = blockIdx.z;  // output j = 2+z
  const float* fj = z ? feat3 : feat2;
  float* oj = out + 33554432ul + (size_t)z * 4194304;
  int tid = threadIdx.x;
  int M0 = blockIdx.x * 128, N0 = blockIdx.y * 128;
  int sel = (cond[5 + 2 * z] > 0.5f) ? 1 : ((cond[4 + 2 * z] > 0.5f) ? 0 : -1);
  if (sel < 0) {  // passthrough copy (uniform per block)
    for (int l = tid; l < 4096; l += 256) {
      int rr = l >> 5, c4 = l & 31;
      size_t idx = (size_t)(M0 + rr) * 1024 + N0 + c4 * 4;
      *(float4*)(oj + idx) = *(const float4*)(fj + idx);
    }
    return;
  }
  const float* A = sel ? feat1 : feat0;
  const bf16* wTz = wT + (size_t)z * 5242880;
  int slot = (sel ? 5 : 4) + 2 * z;
  __shared__ bf16 As[128][72];
  __shared__ bf16 Bs[128][72];
  __shared__ float sld[32];
  if (tid < 32) sld[tid] = score[slot * 32 + tid];
  f32x4 acc[4][4];
  for (int a = 0; a < 4; ++a)
    for (int c = 0; c < 4; ++c) { acc[a][c][0] = 0.f; acc[a][c][1] = 0.f; acc[a][c][2] = 0.f; acc[a][c][3] = 0.f; }
  int row = tid >> 1, half = tid & 1;
  int m = M0 + row, t = m >> 5, b = m & 31;
  int lane = tid & 63, wv = tid >> 6;
  int wr = (wv >> 1) * 64, wc = (wv & 1) * 64;
  int rl = lane & 15, q = lane >> 4;
  for (int kt = 0; kt < 80; ++kt) {
    int kk = kt >> 4, ci0 = (kt & 15) << 6;
    int pos = 4 * t - 2 + kk;  // conv input position, pad=2, stride=4
    __syncthreads();
    {
      float4 v[8];
      if (pos >= 0 && pos < 512) {
        const float4* src = (const float4*)(A + (size_t)(pos * 32 + b) * 1024 + ci0 + half * 32);
        #pragma unroll
        for (int u = 0; u < 8; ++u) v[u] = src[u];
      } else {
        #pragma unroll
        for (int u = 0; u < 8; ++u) v[u] = make_float4(0.f, 0.f, 0.f, 0.f);
      }
      #pragma unroll
      for (int u = 0; u < 4; ++u) {
        bf16x8 pk;
        pk[0] = (bf16)v[2 * u].x; pk[1] = (bf16)v[2 * u].y; pk[2] = (bf16)v[2 * u].z; pk[3] = (bf16)v[2 * u].w;
        pk[4] = (bf16)v[2 * u + 1].x; pk[5] = (bf16)v[2 * u + 1].y; pk[6] = (bf16)v[2 * u + 1].z; pk[7] = (bf16)v[2 * u + 1].w;
        *(bf16x8*)&As[row][half * 32 + u * 8] = pk;
      }
      const uint4* bs = (const uint4*)(wTz + (size_t)(N0 + row) * 5120 + kt * 64 + half * 32);
      #pragma unroll
      for (int u = 0; u < 4; ++u) *(uint4*)&Bs[row][half * 32 + u * 8] = bs[u];
    }
    __syncthreads();
    #pragma unroll
    for (int ks = 0; ks < 2; ++ks) {
      bf16x8 af[4], bfv[4];
      #pragma unroll
      for (int mi = 0; mi < 4; ++mi) af[mi] = *(const bf16x8*)&As[wr + mi * 16 + rl][ks * 32 + q * 8];
      #pragma unroll
      for (int ni = 0; ni < 4; ++ni) bfv[ni] = *(const bf16x8*)&Bs[wc + ni * 16 + rl][ks * 32 + q * 8];
      #pragma unroll
      for (int mi = 0; mi < 4; ++mi)
        #pragma unroll
        for (int ni = 0; ni < 4; ++ni)
          acc[mi][ni] = __builtin_amdgcn_mfma_f32_16x16x32_bf16(af[mi], bfv[ni], acc[mi][ni], 0, 0, 0);
    }
  }
  #pragma unroll
  for (int mi = 0; mi < 4; ++mi)
    #pragma unroll
    for (int ni = 0; ni < 4; ++ni)
      #pragma unroll
      for (int r = 0; r < 4; ++r) {
        int gm = M0 + wr + mi * 16 + q * 4 + r;
        int gn = N0 + wc + ni * 16 + rl;
        size_t idx = (size_t)gm * 1024 + gn;
        oj[idx] = fj[idx] + sld[gm & 31] * acc[mi][ni][r];
      }
}

// ---------------- interp + residual -> out0/out1 ----------------
__global__ __launch_bounds__(256) void k_interp(
    const float* __restrict__ f0, const float* __restrict__ f1,
    const float* __restrict__ proj, const float* __restrict__ score,
    const float* __restrict__ cond, float* __restrict__ out)
{
  int z = blockIdx.y, tb = blockIdx.x, tid = threadIdx.x;  // tb = t*32+b
  const float* fj = z ? f1 : f0;
  float* oj = out + (size_t)z * 16777216;
  int sel = (cond[1 + 2 * z] > 0.5f) ? 3 : ((cond[2 * z] > 0.5f) ? 2 : -1);
  float4 fv = ((const float4*)(fj + (size_t)tb * 1024))[tid];
  if (sel < 0) {
    ((float4*)(oj + (size_t)tb * 1024))[tid] = fv;
    return;
  }
  int t = tb >> 5, b = tb & 31;
  int slot = 2 * z + (sel == 3 ? 1 : 0);
  float s = score[slot * 32 + b];
  // align_corners=False linear interp, 128 -> 512: src = 0.25*t - 0.375, clipped
  float srcf = 0.25f * (float)t - 0.375f;
  srcf = fminf(fmaxf(srcf, 0.f), 127.f);
  int i0 = (int)srcf;
  int i1 = min(i0 + 1, 127);
  float w = srcf - (float)i0;
  const float* pz = proj + (size_t)z * 4194304;
  float4 a = ((const float4*)(pz + (size_t)(i0 * 32 + b) * 1024))[tid];
  float4 c = ((const float4*)(pz + (size_t)(i1 * 32 + b) * 1024))[tid];
  float4 o;
  o.x = fv.x + s * ((1.f - w) * a.x + w * c.x);
  o.y = fv.y + s * ((1.f - w) * a.y + w * c.y);
  o.z = fv.z + s * ((1.f - w) * a.z + w * c.z);
  o.w = fv.w + s * ((1.f - w) * a.w + w * c.w);
  ((float4*)(oj + (size_t)tb * 1024))[tid] = o;
}

// ---------------- launch ----------------
extern "C" void kernel_launch(void* const* d_in, const int* in_sizes, int n_in,
                              void* d_out, int out_size, void* d_ws, size_t ws_size,
                              hipStream_t stream) {
  const float* f0   = (const float*)d_in[0];
  const float* f1   = (const float*)d_in[1];
  const float* f2   = (const float*)d_in[2];
  const float* f3   = (const float*)d_in[3];
  const float* w1   = (const float*)d_in[4];
  const float* b1   = (const float*)d_in[5];
  const float* w2   = (const float*)d_in[6];
  const float* b2   = (const float*)d_in[7];
  const float* s2fw = (const float*)d_in[8];
  const float* s2fb = (const float*)d_in[9];
  const float* f2sw = (const float*)d_in[10];
  float* out = (float*)d_out;

  char* ws = (char*)d_ws;
  float* g     = (float*)(ws + OFF_GLOB);
  float* h_ws  = (float*)(ws + OFF_H);
  float* score = (float*)(ws + OFF_SCORE);
  float* cond  = (float*)(ws + OFF_COND);
  float* part  = (float*)(ws + OFF_PART);
  float* proj  = (float*)(ws + OFF_PROJ);
  bf16*  wtf   = (bf16*)(ws + OFF_WTF2S);
  bf16*  wts   = (bf16*)(ws + OFF_WTS2F);

  hipMemsetAsync(h_ws, 0, 262144, stream);
  k_means_part<<<dim3(32, 8, 4), 256, 0, stream>>>(f0, f1, f2, f3, part);
  k_means_final<<<dim3(32, 4), 256, 0, stream>>>(part, g);
  k_mlp1<<<dim3(8, 8, 4), 256, 0, stream>>>(g, w1, h_ws);
  k_mlp2<<<8, 256, 0, stream>>>(h_ws, b1, w2, b2, score, cond);
  k_f2s_transpose<<<dim3(1024, 2), 256, 0, stream>>>(f2sw, cond, wtf);
  k_s2f_convert<<<1024, 256, 0, stream>>>(s2fw, wts);
  k_s2f_gemm<<<dim3(32, 8, 2), 256, 0, stream>>>(f2, f3, wts, s2fb, cond, proj);
  k_f2s_gemm<<<dim3(32, 8, 2), 256, 0, stream>>>(f0, f1, f2, f3, wtf, score, cond, out);
  k_interp<<<dim3(16384, 2), 256, 0, stream>>>(f0, f1, proj, score, cond, out);
}